// Round 7
// baseline (474.838 us; speedup 1.0000x reference)
//
#include <hip/hip_runtime.h>
#include <hip/hip_bf16.h>
#include <stdint.h>

#define BDIM 8192
#define HDIM 2048
#define KDIM 4096   // IN + H
#define NDIM 6144   // 3 * H

using f32x4  = __attribute__((ext_vector_type(4))) float;
using bf16x8 = __attribute__((ext_vector_type(8))) short;
using short8 = __attribute__((ext_vector_type(8))) short;

__device__ __forceinline__ uint16_t f2bf(float f) {
    union { float f; uint32_t u; } v;
    v.f = f;
    uint32_t r = v.u + 0x7fffu + ((v.u >> 16) & 1u);  // RNE
    return (uint16_t)(r >> 16);
}

__device__ __forceinline__ float bf2f(uint16_t u) {
    union { uint32_t u; float f; } v;
    v.u = ((uint32_t)u) << 16;
    return v.f;
}

__device__ __forceinline__ float fast_sigmoid(float x) {
    return 1.0f / (1.0f + __expf(-x));
}

__device__ __forceinline__ float fast_tanh(float x) {
    float ax = fabsf(x);
    float t = __expf(-2.0f * ax);
    float r = (1.0f - t) / (1.0f + t);
    return copysignf(r, x);
}

// ---------------- fused conversion kernel ----------------
#define XH_CHUNKS ((int64_t)BDIM * KDIM / 4)
#define W_CHUNKS  ((int64_t)3 * HDIM * KDIM / 4)

__global__ void cvt_all_kernel(const float* __restrict__ x,
                               const float* __restrict__ h,
                               const float* __restrict__ Wf,
                               const float* __restrict__ Wo,
                               const float* __restrict__ Wc,
                               uint16_t* __restrict__ xh,
                               uint16_t* __restrict__ Wb) {
    const int64_t total = XH_CHUNKS + W_CHUNKS;
    for (int64_t i = (int64_t)blockIdx.x * blockDim.x + threadIdx.x; i < total;
         i += (int64_t)gridDim.x * blockDim.x) {
        float4 v;
        uint16_t* dst;
        if (i < XH_CHUNKS) {
            int64_t e = i << 2;
            int b = (int)(e >> 12);
            int k = (int)(e & 4095);
            if (k < 2048) v = *(const float4*)(x + (int64_t)b * 2048 + k);
            else          v = *(const float4*)(h + (int64_t)b * 2048 + (k - 2048));
            dst = xh + e;
        } else {
            int64_t e = (i - XH_CHUNKS) << 2;
            const int64_t per_gate = (int64_t)HDIM * KDIM;
            int gate = (int)(e / per_gate);
            int64_t rem = e - (int64_t)gate * per_gate;
            const float* src = (gate == 0) ? Wf : (gate == 1) ? Wo : Wc;
            v = *(const float4*)(src + rem);
            dst = Wb + e;
        }
        ushort4 o;
        o.x = f2bf(v.x); o.y = f2bf(v.y); o.z = f2bf(v.z); o.w = f2bf(v.w);
        *(ushort4*)dst = o;
    }
}

// ---------------- 256x256 4-phase GEMM (32 MFMA / barrier) ---------------
// A: [8192][4096] bf16, Wb: [6144][4096] bf16 (B^T), G out: [8192][6144] bf16
// 8 waves (2M x 4N), per-wave C = 128x64. BK=64. 8-slot LDS ring (128 KiB).
//   A slots: even tile h0->0 h1->1, odd tile h0->2 h1->3
//   B slots: even tile h0->4 h1->5, odd tile h0->6 h1->7
// 4 phases per iteration (2 K-tiles t0,t1), fragment-reuse, split MM in
// Q2/Q4 to recycle bF0 registers without double-buffering:
//   Q1: rd s0(aF t0h0)+s5(bF1 t0h1); stage s3<-A(t1,h1), s4<-B(t2,h0);
//       MM(0,0,bF0pre)+MM(0,1,bF1)
//   Q2: rd s1(aF t0h1); stage s0<-A(t2,h0), s5<-B(t2,h1); MM(1,0,bF0);
//       rd s6(bF0 t1h0); MM(1,1,bF1); WC4
//   Q3: rd s2(aF t1h0)+s7(bF1 t1h1); stage s1<-A(t2,h1), s6<-B(t3,h0);
//       MM(0,0,bF0)+MM(0,1,bF1)
//   Q4: rd s3(aF t1h1); stage s2<-A(t3,h0), s7<-B(t3,h1); MM(1,0,bF0);
//       rd s4(bF0 t2h0, pre-read for next Q1); MM(1,1,bF1); WC4
// Every slot is staged exactly 1 phase after its read (barrier between) and
// 3 phases before its next read. FIFO walk (4 loads/phase, WC4 leaves the
// newest phase's 4): WC4@Q2 completes {s2,s7}(prev Q4) + {s3,s4}(Q1) ->
// covers Q3,Q4 reads; WC4@Q4 completes {s0,s5}(Q2) + {s1,s6}(Q3) -> covers
// next Q1,Q2 reads. 2 waits + 4 barriers per 2 K-tiles.

#define STAGE_A(slot, t, h) do { \
    _Pragma("unroll") for (int q_ = 0; q_ < 2; ++q_) { \
        const int r_ = s_row[q_]; \
        const uint16_t* src_ = A + (int64_t)(m0 + ((r_ >> 6) << 7) + ((h) << 6) + (r_ & 63)) * KDIM + ((t) << 6) + s_kc[q_]; \
        __builtin_amdgcn_global_load_lds((__attribute__((address_space(1))) void*)(src_), \
            (__attribute__((address_space(3))) void*)(&lds[slot][(q_ * 512 + tid) * 8]), 16, 0, 0); \
    } } while (0)

#define STAGE_B(slot, t, h) do { \
    _Pragma("unroll") for (int q_ = 0; q_ < 2; ++q_) { \
        const int r_ = s_row[q_]; \
        const uint16_t* src_ = Wb + (int64_t)(n0 + ((r_ >> 5) << 6) + ((h) << 5) + (r_ & 31)) * KDIM + ((t) << 6) + s_kc[q_]; \
        __builtin_amdgcn_global_load_lds((__attribute__((address_space(1))) void*)(src_), \
            (__attribute__((address_space(3))) void*)(&lds[slot][(q_ * 512 + tid) * 8]), 16, 0, 0); \
    } } while (0)

// read logical (slot, srow, kchunk) with swizzle
#define RD(slot, srow, kc) \
    (*(const bf16x8*)((const char*)(&lds[0][0]) + ((slot) * 16384) + ((srow) * 128) + ((((kc) ^ ((srow) & 7))) * 16)))

#define RD_A(tp, h) do { \
    _Pragma("unroll") for (int kk = 0; kk < 2; ++kk) \
        _Pragma("unroll") for (int mf = 0; mf < 4; ++mf) \
            aF[kk][mf] = RD((((tp) & 1) << 1) + (h), wm * 64 + mf * 16 + fr, kk * 4 + kg); \
} while (0)

#define RD_B(dst, tp, h) do { \
    _Pragma("unroll") for (int kk = 0; kk < 2; ++kk) \
        _Pragma("unroll") for (int nf = 0; nf < 2; ++nf) \
            dst[kk][nf] = RD(4 + (((tp) & 1) << 1) + (h), wn * 32 + nf * 16 + fr, kk * 4 + kg); \
} while (0)

#define MM(qm, qn, bsrc) do { \
    _Pragma("unroll") for (int kk = 0; kk < 2; ++kk) \
        _Pragma("unroll") for (int mf = 0; mf < 4; ++mf) \
            _Pragma("unroll") for (int nf = 0; nf < 2; ++nf) \
                acc[(qm) * 4 + mf][(qn) * 2 + nf] = __builtin_amdgcn_mfma_f32_16x16x32_bf16( \
                    aF[kk][mf], bsrc[kk][nf], acc[(qm) * 4 + mf][(qn) * 2 + nf], 0, 0, 0); \
} while (0)

#define PH4(READS1, STAGE, MM1, READS2, MM2, WAITC) do { \
    asm volatile("" ::: "memory"); \
    READS1; \
    STAGE; \
    asm volatile("" ::: "memory"); \
    __builtin_amdgcn_s_setprio(1); \
    MM1; \
    __builtin_amdgcn_s_setprio(0); \
    asm volatile("" ::: "memory"); \
    READS2; \
    asm volatile("" ::: "memory"); \
    __builtin_amdgcn_s_setprio(1); \
    MM2; \
    __builtin_amdgcn_s_setprio(0); \
    WAITC; \
    __builtin_amdgcn_s_barrier(); \
} while (0)

#define WC4 asm volatile("s_waitcnt vmcnt(4)" ::: "memory")
#define WC0 asm volatile("s_waitcnt vmcnt(0)" ::: "memory")

__global__ __launch_bounds__(512, 2) void lstm_gemm4p_kernel(
    const uint16_t* __restrict__ A,
    const uint16_t* __restrict__ Wb,
    uint16_t* __restrict__ G) {
    __shared__ uint16_t lds[8][8192];  // 128 KiB

    const int tid = threadIdx.x;
    const int lane = tid & 63;
    const int kg = lane >> 4;
    const int fr = lane & 15;
    const int wid = tid >> 6;
    const int wm = wid >> 2;   // 0..1
    const int wn = wid & 3;    // 0..3

    // XCD-aware swizzle: 768 blocks, 768 % 8 == 0 -> simple bijection
    const int bid = blockIdx.x;
    const int swz = (bid & 7) * 96 + (bid >> 3);
    const int mb = swz / 24;
    const int nb = swz - mb * 24;
    const int m0 = mb << 8;
    const int n0 = nb << 8;

    // staging constants: chunk = q*512 + tid -> row, swizzled k-chunk
    int s_row[2], s_kc[2];
#pragma unroll
    for (int q_ = 0; q_ < 2; ++q_) {
        const int chunk = q_ * 512 + tid;
        const int r_ = chunk >> 3;
        const int c_ = chunk & 7;
        s_row[q_] = r_;
        s_kc[q_] = (c_ ^ (r_ & 7)) * 8;  // element offset
    }

    f32x4 acc[8][4] = {};
    bf16x8 aF[2][4];
    bf16x8 bF0[2][2];
    bf16x8 bF1[2][2];

    // prologue: s4(B0h0),s0(A0h0),s5(B0h1),s1(A0h1),s6(B1h0) must complete;
    // s2(A1h0),s7(B1h1) may stay in flight (covered by WC4@Q2 of iter 0).
    STAGE_B(4, 0, 0); STAGE_A(0, 0, 0); STAGE_B(5, 0, 1);
    STAGE_A(1, 0, 1); STAGE_B(6, 1, 0);
    STAGE_A(2, 1, 0); STAGE_B(7, 1, 1);
    WC4;  // completes s4,s0,s5,s1,s6; leaves s2,s7 in flight
    __builtin_amdgcn_s_barrier();
    RD_B(bF0, 0, 0);  // pre-read B(0,h0) from s4
    asm volatile("s_waitcnt lgkmcnt(0)" ::: "memory");
    __builtin_amdgcn_s_barrier();  // s4 safe to re-stage from Q1 on

    // 64 K-tiles, 2 per iteration; i=31 is the peeled tail
    for (int i = 0; i < 31; ++i) {
        const int t0 = 2 * i;
        const int t1 = t0 + 1, t2 = t0 + 2, t3 = t0 + 3;
        PH4(RD_A(t0, 0); RD_B(bF1, t0, 1),
            STAGE_A(3, t1, 1); STAGE_B(4, t2, 0),
            MM(0, 0, bF0); MM(0, 1, bF1), ;, ;, );
        PH4(RD_A(t0, 1),
            STAGE_A(0, t2, 0); STAGE_B(5, t2, 1),
            MM(1, 0, bF0), RD_B(bF0, t1, 0), MM(1, 1, bF1), WC4);
        PH4(RD_A(t1, 0); RD_B(bF1, t1, 1),
            STAGE_A(1, t2, 1); STAGE_B(6, t3, 0),
            MM(0, 0, bF0); MM(0, 1, bF1), ;, ;, );
        PH4(RD_A(t1, 1),
            STAGE_A(2, t3, 0); STAGE_B(7, t3, 1),
            MM(1, 0, bF0), RD_B(bF0, t2, 0), MM(1, 1, bF1), WC4);
    }
    // tail: t0=62, t1=63; stages beyond K dropped; WC0 drains {s2,s7,s3}
    PH4(RD_A(62, 0); RD_B(bF1, 62, 1),
        STAGE_A(3, 63, 1),
        MM(0, 0, bF0); MM(0, 1, bF1), ;, ;, );
    PH4(RD_A(62, 1), ;,
        MM(1, 0, bF0), RD_B(bF0, 63, 0), MM(1, 1, bF1), WC0);
    PH4(RD_A(63, 0); RD_B(bF1, 63, 1), ;,
        MM(0, 0, bF0); MM(0, 1, bF1), ;, ;, );
    PH4(RD_A(63, 1), ;,
        MM(1, 0, bF0), ;, MM(1, 1, bF1), );

    // C-write: D layout col = lane&15, row = (lane>>4)*4 + j
#pragma unroll
    for (int mf = 0; mf < 8; ++mf) {
#pragma unroll
        for (int nf = 0; nf < 4; ++nf) {
            const int n = n0 + wn * 64 + nf * 16 + fr;
            const int64_t mbase = (int64_t)(m0 + wm * 128 + mf * 16 + kg * 4);
#pragma unroll
            for (int j = 0; j < 4; ++j) {
                G[(mbase + j) * NDIM + n] = f2bf(acc[mf][nf][j]);
            }
        }
    }
}

// ---------------- LSTM elementwise epilogue ----------------

__global__ void lstm_epi_kernel(const uint16_t* __restrict__ G,
                                const float* __restrict__ c_prev,
                                const float* __restrict__ b_f,
                                const float* __restrict__ b_o,
                                const float* __restrict__ b_c,
                                float* __restrict__ h_out,
                                float* __restrict__ c_out) {
    const int64_t total = (int64_t)BDIM * HDIM / 8;
    for (int64_t i = (int64_t)blockIdx.x * blockDim.x + threadIdx.x; i < total;
         i += (int64_t)gridDim.x * blockDim.x) {
        const int64_t e = i << 3;
        const int m = (int)(e >> 11);
        const int n = (int)(e & 2047);
        const int64_t gb = (int64_t)m * NDIM + n;
        const short8 fv = *(const short8*)(G + gb);
        const short8 ov = *(const short8*)(G + gb + HDIM);
        const short8 cv = *(const short8*)(G + gb + 2 * HDIM);
        const float4 cp0 = *(const float4*)(c_prev + (int64_t)m * HDIM + n);
        const float4 cp1 = *(const float4*)(c_prev + (int64_t)m * HDIM + n + 4);
        float cp[8] = {cp0.x, cp0.y, cp0.z, cp0.w, cp1.x, cp1.y, cp1.z, cp1.w};
        float hr[8], cr[8];
#pragma unroll
        for (int j = 0; j < 8; ++j) {
            const float fpre = bf2f((uint16_t)fv[j]) + b_f[n + j];
            const float opre = bf2f((uint16_t)ov[j]) + b_o[n + j];
            const float cpre = bf2f((uint16_t)cv[j]) + b_c[n + j];
            const float ft = fast_sigmoid(fpre);
            const float ot = fast_sigmoid(opre);
            const float ch = fast_tanh(cpre);
            const float ct = ft * cp[j] + (1.0f - ft) * ch;
            hr[j] = ot * fast_tanh(ct);
            cr[j] = ct;
        }
        float4 h0 = {hr[0], hr[1], hr[2], hr[3]};
        float4 h1 = {hr[4], hr[5], hr[6], hr[7]};
        float4 c0 = {cr[0], cr[1], cr[2], cr[3]};
        float4 c1 = {cr[4], cr[5], cr[6], cr[7]};
        *(float4*)(h_out + (int64_t)m * HDIM + n) = h0;
        *(float4*)(h_out + (int64_t)m * HDIM + n + 4) = h1;
        *(float4*)(c_out + (int64_t)m * HDIM + n) = c0;
        *(float4*)(c_out + (int64_t)m * HDIM + n + 4) = c1;
    }
}

extern "C" void kernel_launch(void* const* d_in, const int* in_sizes, int n_in,
                              void* d_out, int out_size, void* d_ws, size_t ws_size,
                              hipStream_t stream) {
    const float* x_t   = (const float*)d_in[0];
    const float* h_t_1 = (const float*)d_in[1];
    const float* c_t_1 = (const float*)d_in[2];
    const float* W_f   = (const float*)d_in[3];
    const float* b_f   = (const float*)d_in[4];
    const float* W_o   = (const float*)d_in[5];
    const float* b_o   = (const float*)d_in[6];
    const float* W_c   = (const float*)d_in[7];
    const float* b_c   = (const float*)d_in[8];

    uint16_t* xh  = (uint16_t*)d_ws;                            // 64 MiB
    uint16_t* Wbf = xh + (size_t)BDIM * KDIM;                   // 48 MiB
    uint16_t* G   = Wbf + (size_t)NDIM * KDIM;                  // 96 MiB

    float* h_out = (float*)d_out;
    float* c_out = h_out + (size_t)BDIM * HDIM;

    cvt_all_kernel<<<2048, 256, 0, stream>>>(x_t, h_t_1, W_f, W_o, W_c, xh, Wbf);
    lstm_gemm4p_kernel<<<768, 512, 0, stream>>>(xh, Wbf, G);
    lstm_epi_kernel<<<2048, 256, 0, stream>>>(G, c_t_1, b_f, b_o, b_c,
                                              h_out, c_out);
}